// Round 5
// baseline (1330.320 us; speedup 1.0000x reference)
//
#include <hip/hip_runtime.h>
#include <hip/hip_bf16.h>
#include <math.h>

// Problem: B=128, S=179, E=1024, H=16, D=64.  Inputs fp32, OUTPUT fp32.
#define S_LEN  179
#define M_TOT  22912      // B*S

typedef __attribute__((ext_vector_type(8))) short short8;
typedef __attribute__((ext_vector_type(4))) float f32x4;

__device__ inline unsigned short f2bf(float f) {      // RNE
    union { float f; unsigned int i; } v; v.f = f;
    unsigned int x = v.i;
    unsigned int r = x + 0x7FFFu + ((x >> 16) & 1u);
    return (unsigned short)(r >> 16);
}
// Truncating fp32->bf16 x8 load (hot path; systematic shrink ~2^-9 cancels
// under LayerNorm's scale invariance; random part ~0.2% << 2% threshold).
__device__ inline short8 ldcvt8(const float* p) {
    const float4 f0 = *(const float4*)p;
    const float4 f1 = *(const float4*)(p + 4);
    short8 r;
    r[0] = (short)(__float_as_uint(f0.x) >> 16); r[1] = (short)(__float_as_uint(f0.y) >> 16);
    r[2] = (short)(__float_as_uint(f0.z) >> 16); r[3] = (short)(__float_as_uint(f0.w) >> 16);
    r[4] = (short)(__float_as_uint(f1.x) >> 16); r[5] = (short)(__float_as_uint(f1.y) >> 16);
    r[6] = (short)(__float_as_uint(f1.z) >> 16); r[7] = (short)(__float_as_uint(f1.w) >> 16);
    return r;
}

// Per-wave 48x64 projection: acc[t][nt] = x[qrows(t)] . W[h*64+nt*16+..]^T
// qrows(t) = wave*16 + 64*t + (0..15), clamped to <=178 (garbage rows are
// masked downstream: q>=179 never written, k>=179 gets -inf, P(k>=179)=0).
__device__ inline void proj48(const float* __restrict__ xb,
                              const float* __restrict__ Wm,
                              int h, int wave, int quad, int ln,
                              f32x4 (&acc)[3][4])
{
    #pragma unroll
    for (int t = 0; t < 3; ++t)
        #pragma unroll
        for (int nt = 0; nt < 4; ++nt) acc[t][nt] = (f32x4){0.f, 0.f, 0.f, 0.f};

    const float* wr[4];
    #pragma unroll
    for (int nt = 0; nt < 4; ++nt)
        wr[nt] = Wm + (size_t)(h * 64 + nt * 16 + ln) * 1024;
    const float* xr[3];
    #pragma unroll
    for (int t = 0; t < 3; ++t) {
        int q = wave * 16 + 64 * t + ln;
        if (q > S_LEN - 1) q = S_LEN - 1;
        xr[t] = xb + (size_t)q * 1024;
    }
    for (int kk = 0; kk < 32; ++kk) {
        const int k0 = kk * 32 + quad * 8;
        short8 bfr[4];
        #pragma unroll
        for (int nt = 0; nt < 4; ++nt) bfr[nt] = ldcvt8(wr[nt] + k0);
        short8 af[3];
        #pragma unroll
        for (int t = 0; t < 3; ++t) af[t] = ldcvt8(xr[t] + k0);
        #pragma unroll
        for (int t = 0; t < 3; ++t)
            #pragma unroll
            for (int nt = 0; nt < 4; ++nt)
                acc[t][nt] = __builtin_amdgcn_mfma_f32_16x16x32_bf16(af[t], bfr[nt], acc[t][nt], 0, 0, 0);
    }
}

// ---------------------------------------------------------------------------
// Fused per-(b,h) kernel: QKV projection -> positional-bias attention -> O.
// grid = 2048 (b*16+h), block = 256 (4 waves).  ZERO workspace, fp32 output.
// ---------------------------------------------------------------------------
__global__ __launch_bounds__(256) void fused_attn(
    const float* __restrict__ x,
    const float* __restrict__ Wq,
    const float* __restrict__ Wk,
    const float* __restrict__ Wv,
    float* __restrict__ out)
{
    __shared__ __align__(16) unsigned short Ks[192 * 72];   // K[s][d], stride 72
    __shared__ __align__(16) unsigned short Vt[64 * 200];   // V^T[d][s], stride 200
    __shared__ __align__(16) unsigned short WScr[4][16 * 72]; // per-wave scratch

    const int bh   = blockIdx.x;
    const int b    = bh >> 4;
    const int h    = bh & 15;
    const int wave = threadIdx.x >> 6;
    const int lane = threadIdx.x & 63;
    const int ln   = lane & 15;
    const int quad = lane >> 4;
    const float* xb = x + (size_t)b * S_LEN * 1024;

    f32x4 acc[3][4];
    short8 qa[3][2];
    unsigned short* scr = &WScr[wave][0];

    // ---- Q: project, round-trip per-wave through LDS into A-operand regs ----
    proj48(xb, Wq, h, wave, quad, ln, acc);
    #pragma unroll
    for (int t = 0; t < 3; ++t) {
        #pragma unroll
        for (int nt = 0; nt < 4; ++nt)
            #pragma unroll
            for (int r = 0; r < 4; ++r)
                scr[(quad * 4 + r) * 72 + nt * 16 + ln] = f2bf(acc[t][nt][r]);
        // same-wave DS RAW; compiler inserts lgkmcnt wait
        qa[t][0] = *(const short8*)&scr[ln * 72 + quad * 8];
        qa[t][1] = *(const short8*)&scr[ln * 72 + 32 + quad * 8];
    }

    // ---- K -> LDS (C-layout scatter) ----
    proj48(xb, Wk, h, wave, quad, ln, acc);
    #pragma unroll
    for (int t = 0; t < 3; ++t)
        #pragma unroll
        for (int nt = 0; nt < 4; ++nt)
            #pragma unroll
            for (int r = 0; r < 4; ++r)
                Ks[(wave * 16 + 64 * t + quad * 4 + r) * 72 + nt * 16 + ln] = f2bf(acc[t][nt][r]);

    // ---- V -> LDS transposed ----
    proj48(xb, Wv, h, wave, quad, ln, acc);
    #pragma unroll
    for (int t = 0; t < 3; ++t)
        #pragma unroll
        for (int nt = 0; nt < 4; ++nt)
            #pragma unroll
            for (int r = 0; r < 4; ++r)
                Vt[(nt * 16 + ln) * 200 + wave * 16 + 64 * t + quad * 4 + r] = f2bf(acc[t][nt][r]);

    __syncthreads();

    // ---- attention: 3 strips of 16 q-rows per wave ----
    const float CW = 1.0f / (179.0f * 32.0f);   // scale * w = (E^-0.5) * |q-k|/179
    #pragma unroll 1
    for (int t = 0; t < 3; ++t) {
        const int q0 = wave * 16 + 64 * t;

        f32x4 sc[12];
        #pragma unroll
        for (int i = 0; i < 12; ++i) sc[i] = (f32x4){0.f, 0.f, 0.f, 0.f};
        #pragma unroll
        for (int nt = 0; nt < 12; ++nt) {
            const short8 kb0 = *(const short8*)&Ks[(nt * 16 + ln) * 72 + quad * 8];
            const short8 kb1 = *(const short8*)&Ks[(nt * 16 + ln) * 72 + 32 + quad * 8];
            sc[nt] = __builtin_amdgcn_mfma_f32_16x16x32_bf16(qa[t][0], kb0, sc[nt], 0, 0, 0);
            sc[nt] = __builtin_amdgcn_mfma_f32_16x16x32_bf16(qa[t][1], kb1, sc[nt], 0, 0, 0);
        }

        // mask + positional weight + softmax (row = q, 16 lanes per row)
        float mx[4] = {-INFINITY, -INFINITY, -INFINITY, -INFINITY};
        #pragma unroll
        for (int nt = 0; nt < 12; ++nt) {
            const int k = nt * 16 + ln;
            #pragma unroll
            for (int r = 0; r < 4; ++r) {
                const int q = q0 + quad * 4 + r;
                float v;
                if (k < S_LEN) {
                    int d = q - k; if (d < 0) d = -d;
                    v = sc[nt][r] * ((float)d * CW);
                } else {
                    v = -INFINITY;
                }
                sc[nt][r] = v;
                mx[r] = fmaxf(mx[r], v);
            }
        }
        #pragma unroll
        for (int r = 0; r < 4; ++r) {
            float m = mx[r];
            m = fmaxf(m, __shfl_xor(m, 1));
            m = fmaxf(m, __shfl_xor(m, 2));
            m = fmaxf(m, __shfl_xor(m, 4));
            m = fmaxf(m, __shfl_xor(m, 8));
            mx[r] = m;
        }
        float sum[4] = {0.f, 0.f, 0.f, 0.f};
        #pragma unroll
        for (int nt = 0; nt < 12; ++nt)
            #pragma unroll
            for (int r = 0; r < 4; ++r) {
                const float e = __expf(sc[nt][r] - mx[r]);
                sc[nt][r] = e;
                sum[r] += e;
            }
        #pragma unroll
        for (int r = 0; r < 4; ++r) {
            float s = sum[r];
            s += __shfl_xor(s, 1);
            s += __shfl_xor(s, 2);
            s += __shfl_xor(s, 4);
            s += __shfl_xor(s, 8);
            sum[r] = 1.0f / s;
        }

        // P chunks (C-layout -> per-wave LDS, stride 40 -> A-layout) + PV
        f32x4 o[4];
        #pragma unroll
        for (int i = 0; i < 4; ++i) o[i] = (f32x4){0.f, 0.f, 0.f, 0.f};
        #pragma unroll
        for (int kt = 0; kt < 6; ++kt) {
            #pragma unroll
            for (int c = 0; c < 2; ++c) {
                const int nt = kt * 2 + c;
                #pragma unroll
                for (int r = 0; r < 4; ++r)
                    scr[(quad * 4 + r) * 40 + c * 16 + ln] = f2bf(sc[nt][r] * sum[r]);
            }
            const short8 pa = *(const short8*)&scr[ln * 40 + quad * 8];
            #pragma unroll
            for (int n2 = 0; n2 < 4; ++n2) {
                const short8 vb = *(const short8*)&Vt[(n2 * 16 + ln) * 200 + kt * 32 + quad * 8];
                o[n2] = __builtin_amdgcn_mfma_f32_16x16x32_bf16(pa, vb, o[n2], 0, 0, 0);
            }
        }

        // write O (pre-LN, fp32) to d_out
        #pragma unroll
        for (int n2 = 0; n2 < 4; ++n2) {
            const int col = h * 64 + n2 * 16 + ln;
            #pragma unroll
            for (int r = 0; r < 4; ++r) {
                const int q = q0 + quad * 4 + r;
                if (q < S_LEN)
                    out[((size_t)b * S_LEN + q) * 1024 + col] = o[n2][r];
            }
        }
    }
}

// ---------------------------------------------------------------------------
// In-place fp32 LayerNorm over last dim (1024).  grid = M_TOT rows.
// ---------------------------------------------------------------------------
__global__ __launch_bounds__(256) void ln_kernel(
    float* __restrict__ io,
    const float* __restrict__ g,
    const float* __restrict__ be)
{
    __shared__ float red[8];
    const int row = blockIdx.x;
    const int tid = threadIdx.x;
    float* p = io + (size_t)row * 1024 + tid * 4;

    const float4 u = *(const float4*)p;
    float v[4] = {u.x, u.y, u.z, u.w};
    float sum = 0.f, sq = 0.f;
    #pragma unroll
    for (int j = 0; j < 4; ++j) {
        sum += v[j];
        sq  += v[j] * v[j];
    }
    #pragma unroll
    for (int off = 1; off < 64; off <<= 1) {
        sum += __shfl_xor(sum, off);
        sq  += __shfl_xor(sq, off);
    }
    const int wv = tid >> 6, lane = tid & 63;
    if (lane == 0) { red[wv] = sum; red[4 + wv] = sq; }
    __syncthreads();
    sum = red[0] + red[1] + red[2] + red[3];
    sq  = red[4] + red[5] + red[6] + red[7];
    const float mean = sum * (1.0f / 1024.0f);
    const float var  = fmaxf(sq * (1.0f / 1024.0f) - mean * mean, 0.0f);
    const float inv  = rsqrtf(var + 1e-5f);
    const float4 gg = *(const float4*)(g + tid * 4);
    const float4 bb = *(const float4*)(be + tid * 4);
    float4 o;
    o.x = (v[0] - mean) * inv * gg.x + bb.x;
    o.y = (v[1] - mean) * inv * gg.y + bb.y;
    o.z = (v[2] - mean) * inv * gg.z + bb.z;
    o.w = (v[3] - mean) * inv * gg.w + bb.w;
    *(float4*)p = o;
}

// ---------------------------------------------------------------------------
extern "C" void kernel_launch(void* const* d_in, const int* in_sizes, int n_in,
                              void* d_out, int out_size, void* d_ws, size_t ws_size,
                              hipStream_t stream)
{
    const float* x     = (const float*)d_in[0];
    const float* Wq    = (const float*)d_in[1];
    const float* Wk    = (const float*)d_in[2];
    const float* Wv    = (const float*)d_in[3];
    const float* gamma = (const float*)d_in[4];
    const float* beta  = (const float*)d_in[5];
    float* out = (float*)d_out;   // fp32 output (reference returns fp32)

    (void)d_ws; (void)ws_size;  // zero-workspace design

    fused_attn<<<2048, 256, 0, stream>>>(x, Wq, Wk, Wv, out);
    ln_kernel<<<M_TOT, 256, 0, stream>>>(out, gamma, beta);
}

// Round 6
// 611.037 us; speedup vs baseline: 2.1772x; 2.1772x over previous
//
#include <hip/hip_runtime.h>
#include <hip/hip_bf16.h>
#include <math.h>

// Problem: B=128, S=179, E=1024, H=16, D=64.  Inputs fp32, OUTPUT fp32.
#define S_LEN  179
#define M_TOT  22912      // B*S = 179*128  (exactly 179 tiles of 128 rows!)
#define S_PAD  192

typedef __attribute__((ext_vector_type(8))) short short8;
typedef __attribute__((ext_vector_type(4))) float f32x4;
typedef __attribute__((ext_vector_type(4))) unsigned short ushort4v;

__device__ inline unsigned short f2bf(float f) {      // RNE
    union { float f; unsigned int i; } v; v.f = f;
    unsigned int x = v.i;
    unsigned int r = x + 0x7FFFu + ((x >> 16) & 1u);
    return (unsigned short)(r >> 16);
}
__device__ inline int imin(int a, int b) { return a < b ? a : b; }

// async global->LDS, 16B per lane.  LDS dest must be wave-uniform base + lane*16.
__device__ inline void gl_lds16(const unsigned short* g, unsigned short* l) {
    __builtin_amdgcn_global_load_lds(
        (const __attribute__((address_space(1))) unsigned int*)g,
        (__attribute__((address_space(3))) unsigned int*)l, 16, 0, 0);
}

// ===========================================================================
// FAST PATH (requires ~197.4 MB workspace)
// ===========================================================================

// ---- cast x (22912x1024) and Wq/Wk/Wv (1024x1024 each) fp32 -> bf16 -------
#define XQUADS 5865472        // 22912*1024/4
#define WQUADS 262144         // 1024*1024/4
__global__ __launch_bounds__(256) void cast_all(
    const float* __restrict__ x,
    const float* __restrict__ Wq,
    const float* __restrict__ Wk,
    const float* __restrict__ Wv,
    unsigned short* __restrict__ xb,
    unsigned short* __restrict__ wb)
{
    const int t = blockIdx.x * 256 + threadIdx.x;   // 25984*256 quads exactly
    const float* src;
    unsigned short* dst;
    size_t off;
    if (t < XQUADS) {
        src = x; dst = xb; off = (size_t)t * 4;
    } else {
        const int u = t - XQUADS;
        const int mat = u / WQUADS;
        src = (mat == 0) ? Wq : (mat == 1 ? Wk : Wv);
        dst = wb + (size_t)mat * 1048576;
        off = (size_t)(u - mat * WQUADS) * 4;
    }
    const float4 f = *(const float4*)(src + off);
    ushort4v o;
    o[0] = f2bf(f.x); o[1] = f2bf(f.y); o[2] = f2bf(f.z); o[3] = f2bf(f.w);
    *(ushort4v*)(dst + off) = o;
}

// ---- QKV GEMM, m97 structure: 128x128 tile, BK=64, global_load_lds(16B) ----
// grid = (179, 8, 3); block = 256 (4 waves, 2x2 of 64x64).
// y[m][n] = sum_k xb[m][k] * W[n][k]   (A.B^T, both k-contiguous)
// z=0 -> qb bf16 [M][1024]; z=1 -> kb; z=2 -> vT[b][h][d][s] (s pad 192)
__global__ __launch_bounds__(256) void qkv_gemm2(
    const unsigned short* __restrict__ xb,
    const unsigned short* __restrict__ wb,
    unsigned short* __restrict__ qb,
    unsigned short* __restrict__ kb,
    unsigned short* __restrict__ vT)
{
    __shared__ __align__(16) unsigned short As[128 * 64];   // 16 KB
    __shared__ __align__(16) unsigned short Bs[128 * 64];   // 16 KB

    const int zi = blockIdx.z;
    const unsigned short* W = wb + (size_t)zi * 1048576;
    const int m0 = blockIdx.x * 128;
    const int n0 = blockIdx.y * 128;
    const int tid  = threadIdx.x;
    const int wave = tid >> 6;
    const int lane = tid & 63;
    const int ln   = lane & 15;
    const int quad = lane >> 4;
    const int wm = (wave & 1) * 64;
    const int wn = (wave >> 1) * 64;

    // staging map: thread -> (row = tid/8 + i*32, col8 = (tid%8)*8); per wave
    // the 64 lanes' LDS bytes are base + lane*16 (row*128B + col8*2B).
    const int srow = tid >> 3;
    const int scol = (tid & 7) * 8;
    const unsigned short* ag = xb + (size_t)(m0 + srow) * 1024 + scol;
    const unsigned short* bg = W  + (size_t)(n0 + srow) * 1024 + scol;
    unsigned short* al = &As[srow * 64 + scol];
    unsigned short* bl = &Bs[srow * 64 + scol];

    f32x4 acc[4][4];
    #pragma unroll
    for (int i = 0; i < 4; ++i)
        #pragma unroll
        for (int j = 0; j < 4; ++j) acc[i][j] = (f32x4){0.f, 0.f, 0.f, 0.f};

    for (int kt = 0; kt < 16; ++kt) {
        const int k0 = kt * 64;
        #pragma unroll
        for (int i = 0; i < 4; ++i) {
            gl_lds16(ag + (size_t)i * 32 * 1024 + k0, al + i * 32 * 64);
            gl_lds16(bg + (size_t)i * 32 * 1024 + k0, bl + i * 32 * 64);
        }
        __syncthreads();   // drains vmcnt (global_load_lds) before reads
        #pragma unroll
        for (int kh = 0; kh < 2; ++kh) {
            short8 af[4], bf_[4];
            #pragma unroll
            for (int mi = 0; mi < 4; ++mi)
                af[mi] = *(const short8*)&As[(wm + mi * 16 + ln) * 64 + kh * 32 + quad * 8];
            #pragma unroll
            for (int ni = 0; ni < 4; ++ni)
                bf_[ni] = *(const short8*)&Bs[(wn + ni * 16 + ln) * 64 + kh * 32 + quad * 8];
            #pragma unroll
            for (int mi = 0; mi < 4; ++mi)
                #pragma unroll
                for (int ni = 0; ni < 4; ++ni)
                    acc[mi][ni] = __builtin_amdgcn_mfma_f32_16x16x32_bf16(af[mi], bf_[ni], acc[mi][ni], 0, 0, 0);
        }
        __syncthreads();   // protect LDS reuse next iter
    }

    if (zi < 2) {
        unsigned short* out = (zi == 0) ? qb : kb;
        #pragma unroll
        for (int mi = 0; mi < 4; ++mi)
            #pragma unroll
            for (int ni = 0; ni < 4; ++ni) {
                const int col = n0 + wn + ni * 16 + ln;
                #pragma unroll
                for (int r = 0; r < 4; ++r) {
                    const int row = m0 + wm + mi * 16 + quad * 4 + r;  // C/D: row=quad*4+r, col=ln
                    out[(size_t)row * 1024 + col] = f2bf(acc[mi][ni][r]);
                }
            }
    } else {
        #pragma unroll
        for (int mi = 0; mi < 4; ++mi)
            #pragma unroll
            for (int ni = 0; ni < 4; ++ni) {
                const int col = n0 + wn + ni * 16 + ln;
                const int h = col >> 6, d = col & 63;
                #pragma unroll
                for (int r = 0; r < 4; ++r) {
                    const int row = m0 + wm + mi * 16 + quad * 4 + r;
                    const int b = row / 179;
                    const int s = row - b * 179;
                    vT[(((size_t)b * 16 + h) * 64 + d) * S_PAD + s] = f2bf(acc[mi][ni][r]);
                }
            }
    }
}

// ---- zero vT pad region s in [179,192) ------------------------------------
__global__ void vt_pad_zero(unsigned short* __restrict__ vT)
{
    const int idx = blockIdx.x * 256 + threadIdx.x;  // 8192*256 = 131072*16
    const int row = idx >> 4;
    const int j   = idx & 15;
    if (j < 13)
        vT[(size_t)row * S_PAD + 179 + j] = 0;
}

// ---- attention from precomputed Q/K/vT; fp32 output -----------------------
// grid = (bh=2048, qt=3); block = 256 (4 waves); wave owns 16 q rows.
__global__ __launch_bounds__(256) void attn2(
    const unsigned short* __restrict__ qb,
    const unsigned short* __restrict__ kb,
    const unsigned short* __restrict__ vT,
    float* __restrict__ out)
{
    __shared__ unsigned short pbuf[4][16][208];   // per-wave P tile

    const int bh   = blockIdx.x;
    const int b    = bh >> 4;
    const int h    = bh & 15;
    const int qt   = blockIdx.y;
    const int wave = threadIdx.x >> 6;
    const int lane = threadIdx.x & 63;
    const int ln   = lane & 15;
    const int quad = lane >> 4;
    const int qs   = qt * 64 + wave * 16;
    const size_t mrow = (size_t)b * S_LEN;

    f32x4 sc[12];
    #pragma unroll
    for (int i = 0; i < 12; ++i) sc[i] = (f32x4){0.f, 0.f, 0.f, 0.f};

    const int qoff = imin(qs + ln, S_LEN - 1);       // clamped rows discarded later
    const unsigned short* qrow = qb + (mrow + qoff) * 1024 + h * 64 + quad * 8;
    const short8 a0 = *(const short8*)(qrow);
    const short8 a1 = *(const short8*)(qrow + 32);
    #pragma unroll
    for (int nt = 0; nt < 12; ++nt) {
        const int koffr = imin(nt * 16 + ln, S_LEN - 1);   // masked below
        const unsigned short* krow = kb + (mrow + koffr) * 1024 + h * 64 + quad * 8;
        const short8 b0 = *(const short8*)(krow);
        const short8 b1 = *(const short8*)(krow + 32);
        sc[nt] = __builtin_amdgcn_mfma_f32_16x16x32_bf16(a0, b0, sc[nt], 0, 0, 0);
        sc[nt] = __builtin_amdgcn_mfma_f32_16x16x32_bf16(a1, b1, sc[nt], 0, 0, 0);
    }

    const float CW = 1.0f / (179.0f * 32.0f);   // (E^-0.5) * |q-k|/179
    float mx[4] = {-INFINITY, -INFINITY, -INFINITY, -INFINITY};
    #pragma unroll
    for (int nt = 0; nt < 12; ++nt) {
        const int k = nt * 16 + ln;
        #pragma unroll
        for (int r = 0; r < 4; ++r) {
            const int q = qs + quad * 4 + r;
            float v;
            if (k < S_LEN) {
                int d = q - k; if (d < 0) d = -d;
                v = sc[nt][r] * ((float)d * CW);
            } else {
                v = -INFINITY;
            }
            sc[nt][r] = v;
            mx[r] = fmaxf(mx[r], v);
        }
    }
    #pragma unroll
    for (int r = 0; r < 4; ++r) {
        float m = mx[r];
        m = fmaxf(m, __shfl_xor(m, 1));
        m = fmaxf(m, __shfl_xor(m, 2));
        m = fmaxf(m, __shfl_xor(m, 4));
        m = fmaxf(m, __shfl_xor(m, 8));
        mx[r] = m;
    }
    float sum[4] = {0.f, 0.f, 0.f, 0.f};
    #pragma unroll
    for (int nt = 0; nt < 12; ++nt)
        #pragma unroll
        for (int r = 0; r < 4; ++r) {
            const float e = __expf(sc[nt][r] - mx[r]);
            sc[nt][r] = e;
            sum[r] += e;
        }
    #pragma unroll
    for (int r = 0; r < 4; ++r) {
        float s = sum[r];
        s += __shfl_xor(s, 1);
        s += __shfl_xor(s, 2);
        s += __shfl_xor(s, 4);
        s += __shfl_xor(s, 8);
        sum[r] = 1.0f / s;
    }

    // P: C-layout -> per-wave LDS -> A-layout (no barrier: wave-private, DS in-order)
    #pragma unroll
    for (int nt = 0; nt < 12; ++nt)
        #pragma unroll
        for (int r = 0; r < 4; ++r)
            pbuf[wave][quad * 4 + r][nt * 16 + ln] = f2bf(sc[nt][r] * sum[r]);

    f32x4 o[4];
    #pragma unroll
    for (int i = 0; i < 4; ++i) o[i] = (f32x4){0.f, 0.f, 0.f, 0.f};
    const unsigned short* vbase = vT + (size_t)bh * 64 * S_PAD;
    #pragma unroll
    for (int kt = 0; kt < 6; ++kt) {
        const short8 pa = *(const short8*)&pbuf[wave][ln][kt * 32 + quad * 8];
        #pragma unroll
        for (int n2 = 0; n2 < 4; ++n2) {
            const short8 vb = *(const short8*)(vbase + (size_t)(n2 * 16 + ln) * S_PAD + kt * 32 + quad * 8);
            o[n2] = __builtin_amdgcn_mfma_f32_16x16x32_bf16(pa, vb, o[n2], 0, 0, 0);
        }
    }

    #pragma unroll
    for (int n2 = 0; n2 < 4; ++n2) {
        const int col = h * 64 + n2 * 16 + ln;
        #pragma unroll
        for (int r = 0; r < 4; ++r) {
            const int q = qs + quad * 4 + r;
            if (q < S_LEN)
                out[(mrow + q) * 1024 + col] = o[n2][r];
        }
    }
}

// ===========================================================================
// FALLBACK PATH (round-5 fused kernel, zero workspace) — used if ws too small
// ===========================================================================
__device__ inline short8 ldcvt8(const float* p) {
    const float4 f0 = *(const float4*)p;
    const float4 f1 = *(const float4*)(p + 4);
    short8 r;
    r[0] = (short)(__float_as_uint(f0.x) >> 16); r[1] = (short)(__float_as_uint(f0.y) >> 16);
    r[2] = (short)(__float_as_uint(f0.z) >> 16); r[3] = (short)(__float_as_uint(f0.w) >> 16);
    r[4] = (short)(__float_as_uint(f1.x) >> 16); r[5] = (short)(__float_as_uint(f1.y) >> 16);
    r[6] = (short)(__float_as_uint(f1.z) >> 16); r[7] = (short)(__float_as_uint(f1.w) >> 16);
    return r;
}

__device__ inline void proj48(const float* __restrict__ xb,
                              const float* __restrict__ Wm,
                              int h, int wave, int quad, int ln,
                              f32x4 (&acc)[3][4])
{
    #pragma unroll
    for (int t = 0; t < 3; ++t)
        #pragma unroll
        for (int nt = 0; nt < 4; ++nt) acc[t][nt] = (f32x4){0.f, 0.f, 0.f, 0.f};

    const float* wr[4];
    #pragma unroll
    for (int nt = 0; nt < 4; ++nt)
        wr[nt] = Wm + (size_t)(h * 64 + nt * 16 + ln) * 1024;
    const float* xr[3];
    #pragma unroll
    for (int t = 0; t < 3; ++t) {
        int q = wave * 16 + 64 * t + ln;
        if (q > S_LEN - 1) q = S_LEN - 1;
        xr[t] = xb + (size_t)q * 1024;
    }
    for (int kk = 0; kk < 32; ++kk) {
        const int k0 = kk * 32 + quad * 8;
        short8 bfr[4];
        #pragma unroll
        for (int nt = 0; nt < 4; ++nt) bfr[nt] = ldcvt8(wr[nt] + k0);
        short8 af[3];
        #pragma unroll
        for (int t = 0; t < 3; ++t) af[t] = ldcvt8(xr[t] + k0);
        #pragma unroll
        for (int t = 0; t < 3; ++t)
            #pragma unroll
            for (int nt = 0; nt < 4; ++nt)
                acc[t][nt] = __builtin_amdgcn_mfma_f32_16x16x32_bf16(af[t], bfr[nt], acc[t][nt], 0, 0, 0);
    }
}

__global__ __launch_bounds__(256) void fused_attn(
    const float* __restrict__ x,
    const float* __restrict__ Wq,
    const float* __restrict__ Wk,
    const float* __restrict__ Wv,
    float* __restrict__ out)
{
    __shared__ __align__(16) unsigned short Ks[192 * 72];
    __shared__ __align__(16) unsigned short Vt[64 * 200];
    __shared__ __align__(16) unsigned short WScr[4][16 * 72];

    const int bh   = blockIdx.x;
    const int b    = bh >> 4;
    const int h    = bh & 15;
    const int wave = threadIdx.x >> 6;
    const int lane = threadIdx.x & 63;
    const int ln   = lane & 15;
    const int quad = lane >> 4;
    const float* xb = x + (size_t)b * S_LEN * 1024;

    f32x4 acc[3][4];
    short8 qa[3][2];
    unsigned short* scr = &WScr[wave][0];

    proj48(xb, Wq, h, wave, quad, ln, acc);
    #pragma unroll
    for (int t = 0; t < 3; ++t) {
        #pragma unroll
        for (int nt = 0; nt < 4; ++nt)
            #pragma unroll
            for (int r = 0; r < 4; ++r)
                scr[(quad * 4 + r) * 72 + nt * 16 + ln] = f2bf(acc[t][nt][r]);
        qa[t][0] = *(const short8*)&scr[ln * 72 + quad * 8];
        qa[t][1] = *(const short8*)&scr[ln * 72 + 32 + quad * 8];
    }

    proj48(xb, Wk, h, wave, quad, ln, acc);
    #pragma unroll
    for (int t = 0; t < 3; ++t)
        #pragma unroll
        for (int nt = 0; nt < 4; ++nt)
            #pragma unroll
            for (int r = 0; r < 4; ++r)
                Ks[(wave * 16 + 64 * t + quad * 4 + r) * 72 + nt * 16 + ln] = f2bf(acc[t][nt][r]);

    proj48(xb, Wv, h, wave, quad, ln, acc);
    #pragma unroll
    for (int t = 0; t < 3; ++t)
        #pragma unroll
        for (int nt = 0; nt < 4; ++nt)
            #pragma unroll
            for (int r = 0; r < 4; ++r)
                Vt[(nt * 16 + ln) * 200 + wave * 16 + 64 * t + quad * 4 + r] = f2bf(acc[t][nt][r]);

    __syncthreads();

    const float CW = 1.0f / (179.0f * 32.0f);
    #pragma unroll 1
    for (int t = 0; t < 3; ++t) {
        const int q0 = wave * 16 + 64 * t;

        f32x4 sc[12];
        #pragma unroll
        for (int i = 0; i < 12; ++i) sc[i] = (f32x4){0.f, 0.f, 0.f, 0.f};
        #pragma unroll
        for (int nt = 0; nt < 12; ++nt) {
            const short8 kb0 = *(const short8*)&Ks[(nt * 16 + ln) * 72 + quad * 8];
            const short8 kb1 = *(const short8*)&Ks[(nt * 16 + ln) * 72 + 32 + quad * 8];
            sc[nt] = __builtin_amdgcn_mfma_f32_16x16x32_bf16(qa[t][0], kb0, sc[nt], 0, 0, 0);
            sc[nt] = __builtin_amdgcn_mfma_f32_16x16x32_bf16(qa[t][1], kb1, sc[nt], 0, 0, 0);
        }

        float mx[4] = {-INFINITY, -INFINITY, -INFINITY, -INFINITY};
        #pragma unroll
        for (int nt = 0; nt < 12; ++nt) {
            const int k = nt * 16 + ln;
            #pragma unroll
            for (int r = 0; r < 4; ++r) {
                const int q = q0 + quad * 4 + r;
                float v;
                if (k < S_LEN) {
                    int d = q - k; if (d < 0) d = -d;
                    v = sc[nt][r] * ((float)d * CW);
                } else {
                    v = -INFINITY;
                }
                sc[nt][r] = v;
                mx[r] = fmaxf(mx[r], v);
            }
        }
        #pragma unroll
        for (int r = 0; r < 4; ++r) {
            float m = mx[r];
            m = fmaxf(m, __shfl_xor(m, 1));
            m = fmaxf(m, __shfl_xor(m, 2));
            m = fmaxf(m, __shfl_xor(m, 4));
            m = fmaxf(m, __shfl_xor(m, 8));
            mx[r] = m;
        }
        float sum[4] = {0.f, 0.f, 0.f, 0.f};
        #pragma unroll
        for (int nt = 0; nt < 12; ++nt)
            #pragma unroll
            for (int r = 0; r < 4; ++r) {
                const float e = __expf(sc[nt][r] - mx[r]);
                sc[nt][r] = e;
                sum[r] += e;
            }
        #pragma unroll
        for (int r = 0; r < 4; ++r) {
            float s = sum[r];
            s += __shfl_xor(s, 1);
            s += __shfl_xor(s, 2);
            s += __shfl_xor(s, 4);
            s += __shfl_xor(s, 8);
            sum[r] = 1.0f / s;
        }

        f32x4 o[4];
        #pragma unroll
        for (int i = 0; i < 4; ++i) o[i] = (f32x4){0.f, 0.f, 0.f, 0.f};
        #pragma unroll
        for (int kt = 0; kt < 6; ++kt) {
            #pragma unroll
            for (int c = 0; c < 2; ++c) {
                const int nt = kt * 2 + c;
                #pragma unroll
                for (int r = 0; r < 4; ++r)
                    scr[(quad * 4 + r) * 40 + c * 16 + ln] = f2bf(sc[nt][r] * sum[r]);
            }
            const short8 pa = *(const short8*)&scr[ln * 40 + quad * 8];
            #pragma unroll
            for (int n2 = 0; n2 < 4; ++n2) {
                const short8 vb = *(const short8*)&Vt[(n2 * 16 + ln) * 200 + kt * 32 + quad * 8];
                o[n2] = __builtin_amdgcn_mfma_f32_16x16x32_bf16(pa, vb, o[n2], 0, 0, 0);
            }
        }

        #pragma unroll
        for (int n2 = 0; n2 < 4; ++n2) {
            const int col = h * 64 + n2 * 16 + ln;
            #pragma unroll
            for (int r = 0; r < 4; ++r) {
                const int q = q0 + quad * 4 + r;
                if (q < S_LEN)
                    out[((size_t)b * S_LEN + q) * 1024 + col] = o[n2][r];
            }
        }
    }
}

// ---------------------------------------------------------------------------
// In-place fp32 LayerNorm over last dim (1024).  grid = M_TOT rows.
// ---------------------------------------------------------------------------
__global__ __launch_bounds__(256) void ln_kernel(
    float* __restrict__ io,
    const float* __restrict__ g,
    const float* __restrict__ be)
{
    __shared__ float red[8];
    const int row = blockIdx.x;
    const int tid = threadIdx.x;
    float* p = io + (size_t)row * 1024 + tid * 4;

    const float4 u = *(const float4*)p;
    float v[4] = {u.x, u.y, u.z, u.w};
    float sum = 0.f, sq = 0.f;
    #pragma unroll
    for (int j = 0; j < 4; ++j) {
        sum += v[j];
        sq  += v[j] * v[j];
    }
    #pragma unroll
    for (int off = 1; off < 64; off <<= 1) {
        sum += __shfl_xor(sum, off);
        sq  += __shfl_xor(sq, off);
    }
    const int wv = tid >> 6, lane = tid & 63;
    if (lane == 0) { red[wv] = sum; red[4 + wv] = sq; }
    __syncthreads();
    sum = red[0] + red[1] + red[2] + red[3];
    sq  = red[4] + red[5] + red[6] + red[7];
    const float mean = sum * (1.0f / 1024.0f);
    const float var  = fmaxf(sq * (1.0f / 1024.0f) - mean * mean, 0.0f);
    const float inv  = rsqrtf(var + 1e-5f);
    const float4 gg = *(const float4*)(g + tid * 4);
    const float4 bb = *(const float4*)(be + tid * 4);
    float4 o;
    o.x = (v[0] - mean) * inv * gg.x + bb.x;
    o.y = (v[1] - mean) * inv * gg.y + bb.y;
    o.z = (v[2] - mean) * inv * gg.z + bb.z;
    o.w = (v[3] - mean) * inv * gg.w + bb.w;
    *(float4*)p = o;
}

// ---------------------------------------------------------------------------
extern "C" void kernel_launch(void* const* d_in, const int* in_sizes, int n_in,
                              void* d_out, int out_size, void* d_ws, size_t ws_size,
                              hipStream_t stream)
{
    const float* x     = (const float*)d_in[0];
    const float* Wq    = (const float*)d_in[1];
    const float* Wk    = (const float*)d_in[2];
    const float* Wv    = (const float*)d_in[3];
    const float* gamma = (const float*)d_in[4];
    const float* beta  = (const float*)d_in[5];
    float* out = (float*)d_out;

    const size_t XB  = (size_t)M_TOT * 1024 * 2;          // 46,923,776
    const size_t WBB = (size_t)3 * 1048576 * 2;           //  6,291,456
    const size_t QBB = XB, KBB = XB;
    const size_t VTB = (size_t)2048 * 64 * S_PAD * 2;     // 50,331,648
    const size_t NEED = XB + WBB + QBB + KBB + VTB;       // 197,394,432

    if (ws_size >= NEED) {
        char* ws = (char*)d_ws;
        unsigned short* xb = (unsigned short*)(ws);
        unsigned short* wb = (unsigned short*)(ws + XB);
        unsigned short* qb = (unsigned short*)(ws + XB + WBB);
        unsigned short* kb = (unsigned short*)(ws + XB + WBB + QBB);
        unsigned short* vT = (unsigned short*)(ws + XB + WBB + QBB + KBB);

        cast_all<<<25984, 256, 0, stream>>>(x, Wq, Wk, Wv, xb, wb);
        qkv_gemm2<<<dim3(179, 8, 3), 256, 0, stream>>>(xb, wb, qb, kb, vT);
        vt_pad_zero<<<8192, 256, 0, stream>>>(vT);
        attn2<<<dim3(2048, 3), 256, 0, stream>>>(qb, kb, vT, out);
        ln_kernel<<<M_TOT, 256, 0, stream>>>(out, gamma, beta);
    } else {
        // fallback: validated zero-workspace fused path
        fused_attn<<<2048, 256, 0, stream>>>(x, Wq, Wk, Wv, out);
        ln_kernel<<<M_TOT, 256, 0, stream>>>(out, gamma, beta);
    }
}

// Round 7
// 592.084 us; speedup vs baseline: 2.2468x; 1.0320x over previous
//
#include <hip/hip_runtime.h>
#include <hip/hip_bf16.h>
#include <math.h>

// Problem: B=128, S=179, E=1024, H=16, D=64.  Inputs fp32, OUTPUT fp32.
#define S_LEN  179
#define M_TOT  22912      // B*S = 179*128
#define S_PAD  192

typedef __attribute__((ext_vector_type(8))) short short8;
typedef __attribute__((ext_vector_type(4))) float f32x4;
typedef __attribute__((ext_vector_type(4))) unsigned short ushort4v;

__device__ inline unsigned short f2bf(float f) {      // RNE
    union { float f; unsigned int i; } v; v.f = f;
    unsigned int x = v.i;
    unsigned int r = x + 0x7FFFu + ((x >> 16) & 1u);
    return (unsigned short)(r >> 16);
}
__device__ inline int imin(int a, int b) { return a < b ? a : b; }

// async global->LDS, 16B per lane.  LDS dest must be wave-uniform base + lane*16.
__device__ inline void gl_lds16(const unsigned short* g, unsigned short* l) {
    __builtin_amdgcn_global_load_lds(
        (const __attribute__((address_space(1))) unsigned int*)g,
        (__attribute__((address_space(3))) unsigned int*)l, 16, 0, 0);
}

// ===========================================================================
// FAST PATH (requires ~197.4 MB workspace)
// ===========================================================================

// ---- cast x (22912x1024) and Wq/Wk/Wv (1024x1024 each) fp32 -> bf16 -------
#define XQUADS 5865472        // 22912*1024/4
#define WQUADS 262144         // 1024*1024/4
__global__ __launch_bounds__(256) void cast_all(
    const float* __restrict__ x,
    const float* __restrict__ Wq,
    const float* __restrict__ Wk,
    const float* __restrict__ Wv,
    unsigned short* __restrict__ xb,
    unsigned short* __restrict__ wb)
{
    const int t = blockIdx.x * 256 + threadIdx.x;   // 25984*256 quads exactly
    const float* src;
    unsigned short* dst;
    size_t off;
    if (t < XQUADS) {
        src = x; dst = xb; off = (size_t)t * 4;
    } else {
        const int u = t - XQUADS;
        const int mat = u / WQUADS;
        src = (mat == 0) ? Wq : (mat == 1 ? Wk : Wv);
        dst = wb + (size_t)mat * 1048576;
        off = (size_t)(u - mat * WQUADS) * 4;
    }
    const float4 f = *(const float4*)(src + off);
    ushort4v o;
    o[0] = f2bf(f.x); o[1] = f2bf(f.y); o[2] = f2bf(f.z); o[3] = f2bf(f.w);
    *(ushort4v*)(dst + off) = o;
}

// ---- QKV GEMM, m97 structure + XOR-swizzled LDS (bank-conflict-free) ------
// grid = (179, 8, 3); block = 256 (4 waves, 2x2 of 64x64).
// y[m][n] = sum_k xb[m][k] * W[n][k]   (A.B^T, both k-contiguous)
// LDS layout: row r's logical 16B k-chunk c stored at physical chunk c^(r&7).
// Staging (global side carries the inverse permutation; LDS side unchanged
// wave-uniform base + lane*16):  lane L of each wave-instr covers
// (row = L>>3, physical chunk = L&7) -> fetches logical chunk (L&7)^(L>>3).
// Fragment reads hit physical chunk (kh*4+quad)^(ln&7): 8 bank-groups across
// 16 lanes -> 2-way aliasing = free [m136].
__global__ __launch_bounds__(256) void qkv_gemm2(
    const unsigned short* __restrict__ xb,
    const unsigned short* __restrict__ wb,
    unsigned short* __restrict__ qb,
    unsigned short* __restrict__ kb,
    unsigned short* __restrict__ vT)
{
    __shared__ __align__(16) unsigned short As[128 * 64];   // 16 KB
    __shared__ __align__(16) unsigned short Bs[128 * 64];   // 16 KB

    const int zi = blockIdx.z;
    const unsigned short* W = wb + (size_t)zi * 1048576;
    const int m0 = blockIdx.x * 128;
    const int n0 = blockIdx.y * 128;
    const int tid  = threadIdx.x;
    const int wave = tid >> 6;
    const int lane = tid & 63;
    const int ln   = lane & 15;
    const int quad = lane >> 4;
    const int wm = (wave & 1) * 64;
    const int wn = (wave >> 1) * 64;

    // staging: physical slot (row=tid>>3, chunk=tid&7); global source carries
    // the XOR permutation.
    const int srow  = tid >> 3;
    const int pchunk = tid & 7;
    const int lchunk = pchunk ^ (srow & 7);
    const unsigned short* ag = xb + (size_t)(m0 + srow) * 1024 + lchunk * 8;
    const unsigned short* bg = W  + (size_t)(n0 + srow) * 1024 + lchunk * 8;
    unsigned short* al = &As[srow * 64 + pchunk * 8];
    unsigned short* bl = &Bs[srow * 64 + pchunk * 8];

    f32x4 acc[4][4];
    #pragma unroll
    for (int i = 0; i < 4; ++i)
        #pragma unroll
        for (int j = 0; j < 4; ++j) acc[i][j] = (f32x4){0.f, 0.f, 0.f, 0.f};

    for (int kt = 0; kt < 16; ++kt) {
        const int k0 = kt * 64;
        #pragma unroll
        for (int i = 0; i < 4; ++i) {
            gl_lds16(ag + (size_t)i * 32 * 1024 + k0, al + i * 32 * 64);
            gl_lds16(bg + (size_t)i * 32 * 1024 + k0, bl + i * 32 * 64);
        }
        __syncthreads();   // drains vmcnt (global_load_lds) before reads
        #pragma unroll
        for (int kh = 0; kh < 2; ++kh) {
            short8 af[4], bf_[4];
            #pragma unroll
            for (int mi = 0; mi < 4; ++mi) {
                const int row = wm + mi * 16 + ln;
                const int pc  = (kh * 4 + quad) ^ (ln & 7);
                af[mi] = *(const short8*)&As[row * 64 + pc * 8];
            }
            #pragma unroll
            for (int ni = 0; ni < 4; ++ni) {
                const int row = wn + ni * 16 + ln;
                const int pc  = (kh * 4 + quad) ^ (ln & 7);
                bf_[ni] = *(const short8*)&Bs[row * 64 + pc * 8];
            }
            #pragma unroll
            for (int mi = 0; mi < 4; ++mi)
                #pragma unroll
                for (int ni = 0; ni < 4; ++ni)
                    acc[mi][ni] = __builtin_amdgcn_mfma_f32_16x16x32_bf16(af[mi], bf_[ni], acc[mi][ni], 0, 0, 0);
        }
        __syncthreads();   // protect LDS reuse next iter
    }

    if (zi < 2) {
        unsigned short* out = (zi == 0) ? qb : kb;
        #pragma unroll
        for (int mi = 0; mi < 4; ++mi)
            #pragma unroll
            for (int ni = 0; ni < 4; ++ni) {
                const int col = n0 + wn + ni * 16 + ln;
                #pragma unroll
                for (int r = 0; r < 4; ++r) {
                    const int row = m0 + wm + mi * 16 + quad * 4 + r;  // C/D: row=quad*4+r, col=ln
                    out[(size_t)row * 1024 + col] = f2bf(acc[mi][ni][r]);
                }
            }
    } else {
        #pragma unroll
        for (int mi = 0; mi < 4; ++mi)
            #pragma unroll
            for (int ni = 0; ni < 4; ++ni) {
                const int col = n0 + wn + ni * 16 + ln;
                const int h = col >> 6, d = col & 63;
                #pragma unroll
                for (int r = 0; r < 4; ++r) {
                    const int row = m0 + wm + mi * 16 + quad * 4 + r;
                    const int b = row / 179;
                    const int s = row - b * 179;
                    vT[(((size_t)b * 16 + h) * 64 + d) * S_PAD + s] = f2bf(acc[mi][ni][r]);
                }
            }
    }
}

// ---- zero vT pad region s in [179,192) ------------------------------------
__global__ void vt_pad_zero(unsigned short* __restrict__ vT)
{
    const int idx = blockIdx.x * 256 + threadIdx.x;  // 8192*256 = 131072*16
    const int row = idx >> 4;
    const int j   = idx & 15;
    if (j < 13)
        vT[(size_t)row * S_PAD + 179 + j] = 0;
}

// ---- attention from precomputed Q/K/vT; fp32 output -----------------------
// grid = (bh=2048, qt=3); block = 256 (4 waves); wave owns 16 q rows.
__global__ __launch_bounds__(256) void attn2(
    const unsigned short* __restrict__ qb,
    const unsigned short* __restrict__ kb,
    const unsigned short* __restrict__ vT,
    float* __restrict__ out)
{
    __shared__ unsigned short pbuf[4][16][208];   // per-wave P tile

    const int bh   = blockIdx.x;
    const int b    = bh >> 4;
    const int h    = bh & 15;
    const int qt   = blockIdx.y;
    const int wave = threadIdx.x >> 6;
    const int lane = threadIdx.x & 63;
    const int ln   = lane & 15;
    const int quad = lane >> 4;
    const int qs   = qt * 64 + wave * 16;
    const size_t mrow = (size_t)b * S_LEN;

    f32x4 sc[12];
    #pragma unroll
    for (int i = 0; i < 12; ++i) sc[i] = (f32x4){0.f, 0.f, 0.f, 0.f};

    const int qoff = imin(qs + ln, S_LEN - 1);       // clamped rows discarded later
    const unsigned short* qrow = qb + (mrow + qoff) * 1024 + h * 64 + quad * 8;
    const short8 a0 = *(const short8*)(qrow);
    const short8 a1 = *(const short8*)(qrow + 32);
    #pragma unroll
    for (int nt = 0; nt < 12; ++nt) {
        const int koffr = imin(nt * 16 + ln, S_LEN - 1);   // masked below
        const unsigned short* krow = kb + (mrow + koffr) * 1024 + h * 64 + quad * 8;
        const short8 b0 = *(const short8*)(krow);
        const short8 b1 = *(const short8*)(krow + 32);
        sc[nt] = __builtin_amdgcn_mfma_f32_16x16x32_bf16(a0, b0, sc[nt], 0, 0, 0);
        sc[nt] = __builtin_amdgcn_mfma_f32_16x16x32_bf16(a1, b1, sc[nt], 0, 0, 0);
    }

    const float CW = 1.0f / (179.0f * 32.0f);   // (E^-0.5) * |q-k|/179
    float mx[4] = {-INFINITY, -INFINITY, -INFINITY, -INFINITY};
    #pragma unroll
    for (int nt = 0; nt < 12; ++nt) {
        const int k = nt * 16 + ln;
        #pragma unroll
        for (int r = 0; r < 4; ++r) {
            const int q = qs + quad * 4 + r;
            float v;
            if (k < S_LEN) {
                int d = q - k; if (d < 0) d = -d;
                v = sc[nt][r] * ((float)d * CW);
            } else {
                v = -INFINITY;
            }
            sc[nt][r] = v;
            mx[r] = fmaxf(mx[r], v);
        }
    }
    #pragma unroll
    for (int r = 0; r < 4; ++r) {
        float m = mx[r];
        m = fmaxf(m, __shfl_xor(m, 1));
        m = fmaxf(m, __shfl_xor(m, 2));
        m = fmaxf(m, __shfl_xor(m, 4));
        m = fmaxf(m, __shfl_xor(m, 8));
        mx[r] = m;
    }
    float sum[4] = {0.f, 0.f, 0.f, 0.f};
    #pragma unroll
    for (int nt = 0; nt < 12; ++nt)
        #pragma unroll
        for (int r = 0; r < 4; ++r) {
            const float e = __expf(sc[nt][r] - mx[r]);
            sc[nt][r] = e;
            sum[r] += e;
        }
    #pragma unroll
    for (int r = 0; r < 4; ++r) {
        float s = sum[r];
        s += __shfl_xor(s, 1);
        s += __shfl_xor(s, 2);
        s += __shfl_xor(s, 4);
        s += __shfl_xor(s, 8);
        sum[r] = 1.0f / s;
    }

    // P: C-layout -> per-wave LDS -> A-layout (no barrier: wave-private, DS in-order)
    #pragma unroll
    for (int nt = 0; nt < 12; ++nt)
        #pragma unroll
        for (int r = 0; r < 4; ++r)
            pbuf[wave][quad * 4 + r][nt * 16 + ln] = f2bf(sc[nt][r] * sum[r]);

    f32x4 o[4];
    #pragma unroll
    for (int i = 0; i < 4; ++i) o[i] = (f32x4){0.f, 0.f, 0.f, 0.f};
    const unsigned short* vbase = vT + (size_t)bh * 64 * S_PAD;
    #pragma unroll
    for (int kt = 0; kt < 6; ++kt) {
        const short8 pa = *(const short8*)&pbuf[wave][ln][kt * 32 + quad * 8];
        #pragma unroll
        for (int n2 = 0; n2 < 4; ++n2) {
            const short8 vb = *(const short8*)(vbase + (size_t)(n2 * 16 + ln) * S_PAD + kt * 32 + quad * 8);
            o[n2] = __builtin_amdgcn_mfma_f32_16x16x32_bf16(pa, vb, o[n2], 0, 0, 0);
        }
    }

    #pragma unroll
    for (int n2 = 0; n2 < 4; ++n2) {
        const int col = h * 64 + n2 * 16 + ln;
        #pragma unroll
        for (int r = 0; r < 4; ++r) {
            const int q = qs + quad * 4 + r;
            if (q < S_LEN)
                out[(mrow + q) * 1024 + col] = o[n2][r];
        }
    }
}

// ===========================================================================
// FALLBACK PATH (round-5 fused kernel, zero workspace) — used if ws too small
// ===========================================================================
__device__ inline short8 ldcvt8(const float* p) {
    const float4 f0 = *(const float4*)p;
    const float4 f1 = *(const float4*)(p + 4);
    short8 r;
    r[0] = (short)(__float_as_uint(f0.x) >> 16); r[1] = (short)(__float_as_uint(f0.y) >> 16);
    r[2] = (short)(__float_as_uint(f0.z) >> 16); r[3] = (short)(__float_as_uint(f0.w) >> 16);
    r[4] = (short)(__float_as_uint(f1.x) >> 16); r[5] = (short)(__float_as_uint(f1.y) >> 16);
    r[6] = (short)(__float_as_uint(f1.z) >> 16); r[7] = (short)(__float_as_uint(f1.w) >> 16);
    return r;
}

__device__ inline void proj48(const float* __restrict__ xb,
                              const float* __restrict__ Wm,
                              int h, int wave, int quad, int ln,
                              f32x4 (&acc)[3][4])
{
    #pragma unroll
    for (int t = 0; t < 3; ++t)
        #pragma unroll
        for (int nt = 0; nt < 4; ++nt) acc[t][nt] = (f32x4){0.f, 0.f, 0.f, 0.f};

    const float* wr[4];
    #pragma unroll
    for (int nt = 0; nt < 4; ++nt)
        wr[nt] = Wm + (size_t)(h * 64 + nt * 16 + ln) * 1024;
    const float* xr[3];
    #pragma unroll
    for (int t = 0; t < 3; ++t) {
        int q = wave * 16 + 64 * t + ln;
        if (q > S_LEN - 1) q = S_LEN - 1;
        xr[t] = xb + (size_t)q * 1024;
    }
    for (int kk = 0; kk < 32; ++kk) {
        const int k0 = kk * 32 + quad * 8;
        short8 bfr[4];
        #pragma unroll
        for (int nt = 0; nt < 4; ++nt) bfr[nt] = ldcvt8(wr[nt] + k0);
        short8 af[3];
        #pragma unroll
        for (int t = 0; t < 3; ++t) af[t] = ldcvt8(xr[t] + k0);
        #pragma unroll
        for (int t = 0; t < 3; ++t)
            #pragma unroll
            for (int nt = 0; nt < 4; ++nt)
                acc[t][nt] = __builtin_amdgcn_mfma_f32_16x16x32_bf16(af[t], bfr[nt], acc[t][nt], 0, 0, 0);
    }
}

__global__ __launch_bounds__(256) void fused_attn(
    const float* __restrict__ x,
    const float* __restrict__ Wq,
    const float* __restrict__ Wk,
    const float* __restrict__ Wv,
    float* __restrict__ out)
{
    __shared__ __align__(16) unsigned short Ks[192 * 72];
    __shared__ __align__(16) unsigned short Vt[64 * 200];
    __shared__ __align__(16) unsigned short WScr[4][16 * 72];

    const int bh   = blockIdx.x;
    const int b    = bh >> 4;
    const int h    = bh & 15;
    const int wave = threadIdx.x >> 6;
    const int lane = threadIdx.x & 63;
    const int ln   = lane & 15;
    const int quad = lane >> 4;
    const float* xb = x + (size_t)b * S_LEN * 1024;

    f32x4 acc[3][4];
    short8 qa[3][2];
    unsigned short* scr = &WScr[wave][0];

    proj48(xb, Wq, h, wave, quad, ln, acc);
    #pragma unroll
    for (int t = 0; t < 3; ++t) {
        #pragma unroll
        for (int nt = 0; nt < 4; ++nt)
            #pragma unroll
            for (int r = 0; r < 4; ++r)
                scr[(quad * 4 + r) * 72 + nt * 16 + ln] = f2bf(acc[t][nt][r]);
        qa[t][0] = *(const short8*)&scr[ln * 72 + quad * 8];
        qa[t][1] = *(const short8*)&scr[ln * 72 + 32 + quad * 8];
    }

    proj48(xb, Wk, h, wave, quad, ln, acc);
    #pragma unroll
    for (int t = 0; t < 3; ++t)
        #pragma unroll
        for (int nt = 0; nt < 4; ++nt)
            #pragma unroll
            for (int r = 0; r < 4; ++r)
                Ks[(wave * 16 + 64 * t + quad * 4 + r) * 72 + nt * 16 + ln] = f2bf(acc[t][nt][r]);

    proj48(xb, Wv, h, wave, quad, ln, acc);
    #pragma unroll
    for (int t = 0; t < 3; ++t)
        #pragma unroll
        for (int nt = 0; nt < 4; ++nt)
            #pragma unroll
            for (int r = 0; r < 4; ++r)
                Vt[(nt * 16 + ln) * 200 + wave * 16 + 64 * t + quad * 4 + r] = f2bf(acc[t][nt][r]);

    __syncthreads();

    const float CW = 1.0f / (179.0f * 32.0f);
    #pragma unroll 1
    for (int t = 0; t < 3; ++t) {
        const int q0 = wave * 16 + 64 * t;

        f32x4 sc[12];
        #pragma unroll
        for (int i = 0; i < 12; ++i) sc[i] = (f32x4){0.f, 0.f, 0.f, 0.f};
        #pragma unroll
        for (int nt = 0; nt < 12; ++nt) {
            const short8 kb0 = *(const short8*)&Ks[(nt * 16 + ln) * 72 + quad * 8];
            const short8 kb1 = *(const short8*)&Ks[(nt * 16 + ln) * 72 + 32 + quad * 8];
            sc[nt] = __builtin_amdgcn_mfma_f32_16x16x32_bf16(qa[t][0], kb0, sc[nt], 0, 0, 0);
            sc[nt] = __builtin_amdgcn_mfma_f32_16x16x32_bf16(qa[t][1], kb1, sc[nt], 0, 0, 0);
        }

        float mx[4] = {-INFINITY, -INFINITY, -INFINITY, -INFINITY};
        #pragma unroll
        for (int nt = 0; nt < 12; ++nt) {
            const int k = nt * 16 + ln;
            #pragma unroll
            for (int r = 0; r < 4; ++r) {
                const int q = q0 + quad * 4 + r;
                float v;
                if (k < S_LEN) {
                    int d = q - k; if (d < 0) d = -d;
                    v = sc[nt][r] * ((float)d * CW);
                } else {
                    v = -INFINITY;
                }
                sc[nt][r] = v;
                mx[r] = fmaxf(mx[r], v);
            }
        }
        #pragma unroll
        for (int r = 0; r < 4; ++r) {
            float m = mx[r];
            m = fmaxf(m, __shfl_xor(m, 1));
            m = fmaxf(m, __shfl_xor(m, 2));
            m = fmaxf(m, __shfl_xor(m, 4));
            m = fmaxf(m, __shfl_xor(m, 8));
            mx[r] = m;
        }
        float sum[4] = {0.f, 0.f, 0.f, 0.f};
        #pragma unroll
        for (int nt = 0; nt < 12; ++nt)
            #pragma unroll
            for (int r = 0; r < 4; ++r) {
                const float e = __expf(sc[nt][r] - mx[r]);
                sc[nt][r] = e;
                sum[r] += e;
            }
        #pragma unroll
        for (int r = 0; r < 4; ++r) {
            float s = sum[r];
            s += __shfl_xor(s, 1);
            s += __shfl_xor(s, 2);
            s += __shfl_xor(s, 4);
            s += __shfl_xor(s, 8);
            sum[r] = 1.0f / s;
        }

        f32x4 o[4];
        #pragma unroll
        for (int i = 0; i < 4; ++i) o[i] = (f32x4){0.f, 0.f, 0.f, 0.f};
        #pragma unroll
        for (int kt = 0; kt < 6; ++kt) {
            #pragma unroll
            for (int c = 0; c < 2; ++c) {
                const int nt = kt * 2 + c;
                #pragma unroll
                for (int r = 0; r < 4; ++r)
                    scr[(quad * 4 + r) * 40 + c * 16 + ln] = f2bf(sc[nt][r] * sum[r]);
            }
            const short8 pa = *(const short8*)&scr[ln * 40 + quad * 8];
            #pragma unroll
            for (int n2 = 0; n2 < 4; ++n2) {
                const short8 vb = *(const short8*)&Vt[(n2 * 16 + ln) * 200 + kt * 32 + quad * 8];
                o[n2] = __builtin_amdgcn_mfma_f32_16x16x32_bf16(pa, vb, o[n2], 0, 0, 0);
            }
        }

        #pragma unroll
        for (int n2 = 0; n2 < 4; ++n2) {
            const int col = h * 64 + n2 * 16 + ln;
            #pragma unroll
            for (int r = 0; r < 4; ++r) {
                const int q = q0 + quad * 4 + r;
                if (q < S_LEN)
                    out[((size_t)b * S_LEN + q) * 1024 + col] = o[n2][r];
            }
        }
    }
}

// ---------------------------------------------------------------------------
// In-place fp32 LayerNorm over last dim (1024).  grid = M_TOT rows.
// ---------------------------------------------------------------------------
__global__ __launch_bounds__(256) void ln_kernel(
    float* __restrict__ io,
    const float* __restrict__ g,
    const float* __restrict__ be)
{
    __shared__ float red[8];
    const int row = blockIdx.x;
    const int tid = threadIdx.x;
    float* p = io + (size_t)row * 1024 + tid * 4;

    const float4 u = *(const float4*)p;
    float v[4] = {u.x, u.y, u.z, u.w};
    float sum = 0.f, sq = 0.f;
    #pragma unroll
    for (int j = 0; j < 4; ++j) {
        sum += v[j];
        sq  += v[j] * v[j];
    }
    #pragma unroll
    for (int off = 1; off < 64; off <<= 1) {
        sum += __shfl_xor(sum, off);
        sq  += __shfl_xor(sq, off);
    }
    const int wv = tid >> 6, lane = tid & 63;
    if (lane == 0) { red[wv] = sum; red[4 + wv] = sq; }
    __syncthreads();
    sum = red[0] + red[1] + red[2] + red[3];
    sq  = red[4] + red[5] + red[6] + red[7];
    const float mean = sum * (1.0f / 1024.0f);
    const float var  = fmaxf(sq * (1.0f / 1024.0f) - mean * mean, 0.0f);
    const float inv  = rsqrtf(var + 1e-5f);
    const float4 gg = *(const float4*)(g + tid * 4);
    const float4 bb = *(const float4*)(be + tid * 4);
    float4 o;
    o.x = (v[0] - mean) * inv * gg.x + bb.x;
    o.y = (v[1] - mean) * inv * gg.y + bb.y;
    o.z = (v[2] - mean) * inv * gg.z + bb.z;
    o.w = (v[3] - mean) * inv * gg.w + bb.w;
    *(float4*)p = o;
}

// ---------------------------------------------------------------------------
extern "C" void kernel_launch(void* const* d_in, const int* in_sizes, int n_in,
                              void* d_out, int out_size, void* d_ws, size_t ws_size,
                              hipStream_t stream)
{
    const float* x     = (const float*)d_in[0];
    const float* Wq    = (const float*)d_in[1];
    const float* Wk    = (const float*)d_in[2];
    const float* Wv    = (const float*)d_in[3];
    const float* gamma = (const float*)d_in[4];
    const float* beta  = (const float*)d_in[5];
    float* out = (float*)d_out;

    const size_t XB  = (size_t)M_TOT * 1024 * 2;          // 46,923,776
    const size_t WBB = (size_t)3 * 1048576 * 2;           //  6,291,456
    const size_t QBB = XB, KBB = XB;
    const size_t VTB = (size_t)2048 * 64 * S_PAD * 2;     // 50,331,648
    const size_t NEED = XB + WBB + QBB + KBB + VTB;       // 197,394,432

    if (ws_size >= NEED) {
        char* ws = (char*)d_ws;
        unsigned short* xb = (unsigned short*)(ws);
        unsigned short* wb = (unsigned short*)(ws + XB);
        unsigned short* qb = (unsigned short*)(ws + XB + WBB);
        unsigned short* kb = (unsigned short*)(ws + XB + WBB + QBB);
        unsigned short* vT = (unsigned short*)(ws + XB + WBB + QBB + KBB);

        cast_all<<<25984, 256, 0, stream>>>(x, Wq, Wk, Wv, xb, wb);
        qkv_gemm2<<<dim3(179, 8, 3), 256, 0, stream>>>(xb, wb, qb, kb, vT);
        vt_pad_zero<<<8192, 256, 0, stream>>>(vT);
        attn2<<<dim3(2048, 3), 256, 0, stream>>>(qb, kb, vT, out);
        ln_kernel<<<M_TOT, 256, 0, stream>>>(out, gamma, beta);
    } else {
        // fallback: validated zero-workspace fused path
        fused_attn<<<2048, 256, 0, stream>>>(x, Wq, Wk, Wv, out);
        ln_kernel<<<M_TOT, 256, 0, stream>>>(out, gamma, beta);
    }
}

// Round 8
// 510.977 us; speedup vs baseline: 2.6035x; 1.1587x over previous
//
#include <hip/hip_runtime.h>
#include <hip/hip_bf16.h>
#include <math.h>

// Problem: B=128, S=179, E=1024, H=16, D=64.  Inputs fp32, OUTPUT fp32.
#define S_LEN  179
#define M_TOT  22912      // B*S = 179*128
#define S_PAD  192

typedef __attribute__((ext_vector_type(8))) short short8;
typedef __attribute__((ext_vector_type(4))) float f32x4;
typedef __attribute__((ext_vector_type(4))) unsigned short ushort4v;

__device__ inline unsigned short f2bf(float f) {      // RNE
    union { float f; unsigned int i; } v; v.f = f;
    unsigned int x = v.i;
    unsigned int r = x + 0x7FFFu + ((x >> 16) & 1u);
    return (unsigned short)(r >> 16);
}
__device__ inline int imin(int a, int b) { return a < b ? a : b; }

// async global->LDS, 16B per lane.  LDS dest must be wave-uniform base + lane*16.
__device__ inline void gl_lds16(const unsigned short* g, unsigned short* l) {
    __builtin_amdgcn_global_load_lds(
        (const __attribute__((address_space(1))) unsigned int*)g,
        (__attribute__((address_space(3))) unsigned int*)l, 16, 0, 0);
}

// ===========================================================================
// FAST PATH (requires ~197.4 MB workspace)
// ===========================================================================

// ---- cast x (22912x1024) and Wq/Wk/Wv (1024x1024 each) fp32 -> bf16 -------
#define XQUADS 5865472        // 22912*1024/4
#define WQUADS 262144         // 1024*1024/4
__global__ __launch_bounds__(256) void cast_all(
    const float* __restrict__ x,
    const float* __restrict__ Wq,
    const float* __restrict__ Wk,
    const float* __restrict__ Wv,
    unsigned short* __restrict__ xb,
    unsigned short* __restrict__ wb)
{
    const int t = blockIdx.x * 256 + threadIdx.x;   // 25984*256 quads exactly
    const float* src;
    unsigned short* dst;
    size_t off;
    if (t < XQUADS) {
        src = x; dst = xb; off = (size_t)t * 4;
    } else {
        const int u = t - XQUADS;
        const int mat = u / WQUADS;
        src = (mat == 0) ? Wq : (mat == 1 ? Wk : Wv);
        dst = wb + (size_t)mat * 1048576;
        off = (size_t)(u - mat * WQUADS) * 4;
    }
    const float4 f = *(const float4*)(src + off);
    ushort4v o;
    o[0] = f2bf(f.x); o[1] = f2bf(f.y); o[2] = f2bf(f.z); o[3] = f2bf(f.w);
    *(ushort4v*)(dst + off) = o;
}

// ---- QKV GEMM, m97 structure + XOR-swizzled LDS (bank-conflict-free) ------
// grid = (179, 8, 3); block = 256 (4 waves, 2x2 of 64x64).
__global__ __launch_bounds__(256) void qkv_gemm2(
    const unsigned short* __restrict__ xb,
    const unsigned short* __restrict__ wb,
    unsigned short* __restrict__ qb,
    unsigned short* __restrict__ kb,
    unsigned short* __restrict__ vT)
{
    __shared__ __align__(16) unsigned short As[128 * 64];   // 16 KB
    __shared__ __align__(16) unsigned short Bs[128 * 64];   // 16 KB

    const int zi = blockIdx.z;
    const unsigned short* W = wb + (size_t)zi * 1048576;
    const int m0 = blockIdx.x * 128;
    const int n0 = blockIdx.y * 128;
    const int tid  = threadIdx.x;
    const int wave = tid >> 6;
    const int lane = tid & 63;
    const int ln   = lane & 15;
    const int quad = lane >> 4;
    const int wm = (wave & 1) * 64;
    const int wn = (wave >> 1) * 64;

    // staging: physical slot (row=tid>>3, chunk=tid&7); global source carries
    // the XOR permutation (row r's logical chunk c lives at physical c^(r&7)).
    const int srow  = tid >> 3;
    const int pchunk = tid & 7;
    const int lchunk = pchunk ^ (srow & 7);
    const unsigned short* ag = xb + (size_t)(m0 + srow) * 1024 + lchunk * 8;
    const unsigned short* bg = W  + (size_t)(n0 + srow) * 1024 + lchunk * 8;
    unsigned short* al = &As[srow * 64 + pchunk * 8];
    unsigned short* bl = &Bs[srow * 64 + pchunk * 8];

    f32x4 acc[4][4];
    #pragma unroll
    for (int i = 0; i < 4; ++i)
        #pragma unroll
        for (int j = 0; j < 4; ++j) acc[i][j] = (f32x4){0.f, 0.f, 0.f, 0.f};

    for (int kt = 0; kt < 16; ++kt) {
        const int k0 = kt * 64;
        #pragma unroll
        for (int i = 0; i < 4; ++i) {
            gl_lds16(ag + (size_t)i * 32 * 1024 + k0, al + i * 32 * 64);
            gl_lds16(bg + (size_t)i * 32 * 1024 + k0, bl + i * 32 * 64);
        }
        __syncthreads();
        #pragma unroll
        for (int kh = 0; kh < 2; ++kh) {
            short8 af[4], bf_[4];
            #pragma unroll
            for (int mi = 0; mi < 4; ++mi) {
                const int row = wm + mi * 16 + ln;
                const int pc  = (kh * 4 + quad) ^ (ln & 7);
                af[mi] = *(const short8*)&As[row * 64 + pc * 8];
            }
            #pragma unroll
            for (int ni = 0; ni < 4; ++ni) {
                const int row = wn + ni * 16 + ln;
                const int pc  = (kh * 4 + quad) ^ (ln & 7);
                bf_[ni] = *(const short8*)&Bs[row * 64 + pc * 8];
            }
            #pragma unroll
            for (int mi = 0; mi < 4; ++mi)
                #pragma unroll
                for (int ni = 0; ni < 4; ++ni)
                    acc[mi][ni] = __builtin_amdgcn_mfma_f32_16x16x32_bf16(af[mi], bf_[ni], acc[mi][ni], 0, 0, 0);
        }
        __syncthreads();
    }

    if (zi < 2) {
        unsigned short* out = (zi == 0) ? qb : kb;
        #pragma unroll
        for (int mi = 0; mi < 4; ++mi)
            #pragma unroll
            for (int ni = 0; ni < 4; ++ni) {
                const int col = n0 + wn + ni * 16 + ln;
                #pragma unroll
                for (int r = 0; r < 4; ++r) {
                    const int row = m0 + wm + mi * 16 + quad * 4 + r;  // C/D: row=quad*4+r, col=ln
                    out[(size_t)row * 1024 + col] = f2bf(acc[mi][ni][r]);
                }
            }
    } else {
        #pragma unroll
        for (int mi = 0; mi < 4; ++mi)
            #pragma unroll
            for (int ni = 0; ni < 4; ++ni) {
                const int col = n0 + wn + ni * 16 + ln;
                const int h = col >> 6, d = col & 63;
                #pragma unroll
                for (int r = 0; r < 4; ++r) {
                    const int row = m0 + wm + mi * 16 + quad * 4 + r;
                    const int b = row / 179;
                    const int s = row - b * 179;
                    vT[(((size_t)b * 16 + h) * 64 + d) * S_PAD + s] = f2bf(acc[mi][ni][r]);
                }
            }
    }
}

// ---- zero vT pad region s in [179,192) ------------------------------------
__global__ void vt_pad_zero(unsigned short* __restrict__ vT)
{
    const int idx = blockIdx.x * 256 + threadIdx.x;  // 8192*256 = 131072*16
    const int row = idx >> 4;
    const int j   = idx & 15;
    if (j < 13)
        vT[(size_t)row * S_PAD + 179 + j] = 0;
}

// ---- attention v3: one block per (b,h); K & V^T staged to LDS once, -------
// qt fused as a 3-iteration per-wave loop (3x K/V reuse, coalesced staging).
// grid = 2048; block = 256 (4 waves).
__global__ __launch_bounds__(256) void attn3(
    const unsigned short* __restrict__ qb,
    const unsigned short* __restrict__ kb,
    const unsigned short* __restrict__ vT,
    float* __restrict__ out)
{
    __shared__ __align__(16) unsigned short Ks[192 * 72];     // 27.6 KB, stride 72
    __shared__ __align__(16) unsigned short Vs[64 * 200];     // 25.6 KB, stride 200
    __shared__ __align__(16) unsigned short Ps[4][16 * 40];   // per-wave P scratch, 5.1 KB

    const int bh   = blockIdx.x;
    const int b    = bh >> 4;
    const int h    = bh & 15;
    const int tid  = threadIdx.x;
    const int wave = tid >> 6;
    const int lane = tid & 63;
    const int ln   = lane & 15;
    const int quad = lane >> 4;
    const size_t mrow = (size_t)b * S_LEN;
    unsigned short* scr = &Ps[wave][0];

    // ---- stage K[s][d] -> Ks (192 rows, src row clamped to <=178: pad rows
    // hold finite dup data; masked later by -inf) ----
    {
        const int r = tid >> 3;          // 32 rows per pass, 6 passes
        const int c = tid & 7;
        #pragma unroll
        for (int it = 0; it < 6; ++it) {
            const int row = it * 32 + r;
            const int src = imin(row, S_LEN - 1);
            const short8 v = *(const short8*)(kb + (mrow + src) * 1024 + h * 64 + c * 8);
            *(short8*)&Ks[row * 72 + c * 8] = v;
        }
    }
    // ---- stage V^T[d][s] -> Vs (pad s in [179,192) already zeroed in vT) ----
    {
        const unsigned short* vbase = vT + (size_t)bh * 64 * S_PAD;
        #pragma unroll
        for (int it = 0; it < 6; ++it) {
            const int idx = it * 256 + tid;     // 1536 = 64 rows * 24 chunks
            const int d = idx / 24;
            const int c = idx - d * 24;
            const short8 v = *(const short8*)(vbase + (size_t)d * S_PAD + c * 8);
            *(short8*)&Vs[d * 200 + c * 8] = v;
        }
    }
    __syncthreads();

    const float CW = 1.0f / (179.0f * 32.0f);   // (E^-0.5) * |q-k|/179
    #pragma unroll 1
    for (int t = 0; t < 3; ++t) {
        const int qs = t * 64 + wave * 16;      // q strip base

        // Q fragment: global scattered (6 loads/wave total across t)
        const int qoff = imin(qs + ln, S_LEN - 1);
        const unsigned short* qrow = qb + (mrow + qoff) * 1024 + h * 64 + quad * 8;
        const short8 a0 = *(const short8*)(qrow);
        const short8 a1 = *(const short8*)(qrow + 32);

        f32x4 sc[12];
        #pragma unroll
        for (int i = 0; i < 12; ++i) sc[i] = (f32x4){0.f, 0.f, 0.f, 0.f};
        #pragma unroll
        for (int nt = 0; nt < 12; ++nt) {
            // bank check: dword addr = row*36 + kh*16 + quad*4; 36*ln mod 32 =
            // 4*ln -> 8 distinct groups over 16 lanes = 2-way = free.
            const short8 kb0 = *(const short8*)&Ks[(nt * 16 + ln) * 72 + quad * 8];
            const short8 kb1 = *(const short8*)&Ks[(nt * 16 + ln) * 72 + 32 + quad * 8];
            sc[nt] = __builtin_amdgcn_mfma_f32_16x16x32_bf16(a0, kb0, sc[nt], 0, 0, 0);
            sc[nt] = __builtin_amdgcn_mfma_f32_16x16x32_bf16(a1, kb1, sc[nt], 0, 0, 0);
        }

        float mx[4] = {-INFINITY, -INFINITY, -INFINITY, -INFINITY};
        #pragma unroll
        for (int nt = 0; nt < 12; ++nt) {
            const int k = nt * 16 + ln;
            #pragma unroll
            for (int r = 0; r < 4; ++r) {
                const int q = qs + quad * 4 + r;
                float v;
                if (k < S_LEN) {
                    int d = q - k; if (d < 0) d = -d;
                    v = sc[nt][r] * ((float)d * CW);
                } else {
                    v = -INFINITY;
                }
                sc[nt][r] = v;
                mx[r] = fmaxf(mx[r], v);
            }
        }
        #pragma unroll
        for (int r = 0; r < 4; ++r) {
            float m = mx[r];
            m = fmaxf(m, __shfl_xor(m, 1));
            m = fmaxf(m, __shfl_xor(m, 2));
            m = fmaxf(m, __shfl_xor(m, 4));
            m = fmaxf(m, __shfl_xor(m, 8));
            mx[r] = m;
        }
        float sum[4] = {0.f, 0.f, 0.f, 0.f};
        #pragma unroll
        for (int nt = 0; nt < 12; ++nt)
            #pragma unroll
            for (int r = 0; r < 4; ++r) {
                const float e = __expf(sc[nt][r] - mx[r]);
                sc[nt][r] = e;
                sum[r] += e;
            }
        #pragma unroll
        for (int r = 0; r < 4; ++r) {
            float s = sum[r];
            s += __shfl_xor(s, 1);
            s += __shfl_xor(s, 2);
            s += __shfl_xor(s, 4);
            s += __shfl_xor(s, 8);
            sum[r] = 1.0f / s;
        }

        // P: C-layout -> per-wave LDS (stride 40) -> A-layout; PV from Vs
        f32x4 o[4];
        #pragma unroll
        for (int i = 0; i < 4; ++i) o[i] = (f32x4){0.f, 0.f, 0.f, 0.f};
        #pragma unroll
        for (int kt = 0; kt < 6; ++kt) {
            #pragma unroll
            for (int c = 0; c < 2; ++c) {
                const int nt = kt * 2 + c;
                #pragma unroll
                for (int r = 0; r < 4; ++r)
                    scr[(quad * 4 + r) * 40 + c * 16 + ln] = f2bf(sc[nt][r] * sum[r]);
            }
            const short8 pa = *(const short8*)&scr[ln * 40 + quad * 8];
            #pragma unroll
            for (int n2 = 0; n2 < 4; ++n2) {
                // bank: dword = row*100 + ...; 100*ln mod 32 = 4*ln -> 2-way, free
                const short8 vb = *(const short8*)&Vs[(n2 * 16 + ln) * 200 + kt * 32 + quad * 8];
                o[n2] = __builtin_amdgcn_mfma_f32_16x16x32_bf16(pa, vb, o[n2], 0, 0, 0);
            }
        }

        #pragma unroll
        for (int n2 = 0; n2 < 4; ++n2) {
            const int col = h * 64 + n2 * 16 + ln;
            #pragma unroll
            for (int r = 0; r < 4; ++r) {
                const int q = qs + quad * 4 + r;
                if (q < S_LEN)
                    out[(mrow + q) * 1024 + col] = o[n2][r];
            }
        }
    }
}

// ===========================================================================
// FALLBACK PATH (round-5 fused kernel, zero workspace) — used if ws too small
// ===========================================================================
__device__ inline short8 ldcvt8(const float* p) {
    const float4 f0 = *(const float4*)p;
    const float4 f1 = *(const float4*)(p + 4);
    short8 r;
    r[0] = (short)(__float_as_uint(f0.x) >> 16); r[1] = (short)(__float_as_uint(f0.y) >> 16);
    r[2] = (short)(__float_as_uint(f0.z) >> 16); r[3] = (short)(__float_as_uint(f0.w) >> 16);
    r[4] = (short)(__float_as_uint(f1.x) >> 16); r[5] = (short)(__float_as_uint(f1.y) >> 16);
    r[6] = (short)(__float_as_uint(f1.z) >> 16); r[7] = (short)(__float_as_uint(f1.w) >> 16);
    return r;
}

__device__ inline void proj48(const float* __restrict__ xb,
                              const float* __restrict__ Wm,
                              int h, int wave, int quad, int ln,
                              f32x4 (&acc)[3][4])
{
    #pragma unroll
    for (int t = 0; t < 3; ++t)
        #pragma unroll
        for (int nt = 0; nt < 4; ++nt) acc[t][nt] = (f32x4){0.f, 0.f, 0.f, 0.f};

    const float* wr[4];
    #pragma unroll
    for (int nt = 0; nt < 4; ++nt)
        wr[nt] = Wm + (size_t)(h * 64 + nt * 16 + ln) * 1024;
    const float* xr[3];
    #pragma unroll
    for (int t = 0; t < 3; ++t) {
        int q = wave * 16 + 64 * t + ln;
        if (q > S_LEN - 1) q = S_LEN - 1;
        xr[t] = xb + (size_t)q * 1024;
    }
    for (int kk = 0; kk < 32; ++kk) {
        const int k0 = kk * 32 + quad * 8;
        short8 bfr[4];
        #pragma unroll
        for (int nt = 0; nt < 4; ++nt) bfr[nt] = ldcvt8(wr[nt] + k0);
        short8 af[3];
        #pragma unroll
        for (int t = 0; t < 3; ++t) af[t] = ldcvt8(xr[t] + k0);
        #pragma unroll
        for (int t = 0; t < 3; ++t)
            #pragma unroll
            for (int nt = 0; nt < 4; ++nt)
                acc[t][nt] = __builtin_amdgcn_mfma_f32_16x16x32_bf16(af[t], bfr[nt], acc[t][nt], 0, 0, 0);
    }
}

__global__ __launch_bounds__(256) void fused_attn(
    const float* __restrict__ x,
    const float* __restrict__ Wq,
    const float* __restrict__ Wk,
    const float* __restrict__ Wv,
    float* __restrict__ out)
{
    __shared__ __align__(16) unsigned short Ks[192 * 72];
    __shared__ __align__(16) unsigned short Vt[64 * 200];
    __shared__ __align__(16) unsigned short WScr[4][16 * 72];

    const int bh   = blockIdx.x;
    const int b    = bh >> 4;
    const int h    = bh & 15;
    const int wave = threadIdx.x >> 6;
    const int lane = threadIdx.x & 63;
    const int ln   = lane & 15;
    const int quad = lane >> 4;
    const float* xb = x + (size_t)b * S_LEN * 1024;

    f32x4 acc[3][4];
    short8 qa[3][2];
    unsigned short* scr = &WScr[wave][0];

    proj48(xb, Wq, h, wave, quad, ln, acc);
    #pragma unroll
    for (int t = 0; t < 3; ++t) {
        #pragma unroll
        for (int nt = 0; nt < 4; ++nt)
            #pragma unroll
            for (int r = 0; r < 4; ++r)
                scr[(quad * 4 + r) * 72 + nt * 16 + ln] = f2bf(acc[t][nt][r]);
        qa[t][0] = *(const short8*)&scr[ln * 72 + quad * 8];
        qa[t][1] = *(const short8*)&scr[ln * 72 + 32 + quad * 8];
    }

    proj48(xb, Wk, h, wave, quad, ln, acc);
    #pragma unroll
    for (int t = 0; t < 3; ++t)
        #pragma unroll
        for (int nt = 0; nt < 4; ++nt)
            #pragma unroll
            for (int r = 0; r < 4; ++r)
                Ks[(wave * 16 + 64 * t + quad * 4 + r) * 72 + nt * 16 + ln] = f2bf(acc[t][nt][r]);

    proj48(xb, Wv, h, wave, quad, ln, acc);
    #pragma unroll
    for (int t = 0; t < 3; ++t)
        #pragma unroll
        for (int nt = 0; nt < 4; ++nt)
            #pragma unroll
            for (int r = 0; r < 4; ++r)
                Vt[(nt * 16 + ln) * 200 + wave * 16 + 64 * t + quad * 4 + r] = f2bf(acc[t][nt][r]);

    __syncthreads();

    const float CW = 1.0f / (179.0f * 32.0f);
    #pragma unroll 1
    for (int t = 0; t < 3; ++t) {
        const int q0 = wave * 16 + 64 * t;

        f32x4 sc[12];
        #pragma unroll
        for (int i = 0; i < 12; ++i) sc[i] = (f32x4){0.f, 0.f, 0.f, 0.f};
        #pragma unroll
        for (int nt = 0; nt < 12; ++nt) {
            const short8 kb0 = *(const short8*)&Ks[(nt * 16 + ln) * 72 + quad * 8];
            const short8 kb1 = *(const short8*)&Ks[(nt * 16 + ln) * 72 + 32 + quad * 8];
            sc[nt] = __builtin_amdgcn_mfma_f32_16x16x32_bf16(qa[t][0], kb0, sc[nt], 0, 0, 0);
            sc[nt] = __builtin_amdgcn_mfma_f32_16x16x32_bf16(qa[t][1], kb1, sc[nt], 0, 0, 0);
        }

        float mx[4] = {-INFINITY, -INFINITY, -INFINITY, -INFINITY};
        #pragma unroll
        for (int nt = 0; nt < 12; ++nt) {
            const int k = nt * 16 + ln;
            #pragma unroll
            for (int r = 0; r < 4; ++r) {
                const int q = q0 + quad * 4 + r;
                float v;
                if (k < S_LEN) {
                    int d = q - k; if (d < 0) d = -d;
                    v = sc[nt][r] * ((float)d * CW);
                } else {
                    v = -INFINITY;
                }
                sc[nt][r] = v;
                mx[r] = fmaxf(mx[r], v);
            }
        }
        #pragma unroll
        for (int r = 0; r < 4; ++r) {
            float m = mx[r];
            m = fmaxf(m, __shfl_xor(m, 1));
            m = fmaxf(m, __shfl_xor(m, 2));
            m = fmaxf(m, __shfl_xor(m, 4));
            m = fmaxf(m, __shfl_xor(m, 8));
            mx[r] = m;
        }
        float sum[4] = {0.f, 0.f, 0.f, 0.f};
        #pragma unroll
        for (int nt = 0; nt < 12; ++nt)
            #pragma unroll
            for (int r = 0; r < 4; ++r) {
                const float e = __expf(sc[nt][r] - mx[r]);
                sc[nt][r] = e;
                sum[r] += e;
            }
        #pragma unroll
        for (int r = 0; r < 4; ++r) {
            float s = sum[r];
            s += __shfl_xor(s, 1);
            s += __shfl_xor(s, 2);
            s += __shfl_xor(s, 4);
            s += __shfl_xor(s, 8);
            sum[r] = 1.0f / s;
        }

        f32x4 o[4];
        #pragma unroll
        for (int i = 0; i < 4; ++i) o[i] = (f32x4){0.f, 0.f, 0.f, 0.f};
        #pragma unroll
        for (int kt = 0; kt < 6; ++kt) {
            #pragma unroll
            for (int c = 0; c < 2; ++c) {
                const int nt = kt * 2 + c;
                #pragma unroll
                for (int r = 0; r < 4; ++r)
                    scr[(quad * 4 + r) * 40 + c * 16 + ln] = f2bf(sc[nt][r] * sum[r]);
            }
            const short8 pa = *(const short8*)&scr[ln * 40 + quad * 8];
            #pragma unroll
            for (int n2 = 0; n2 < 4; ++n2) {
                const short8 vb = *(const short8*)&Vt[(n2 * 16 + ln) * 200 + kt * 32 + quad * 8];
                o[n2] = __builtin_amdgcn_mfma_f32_16x16x32_bf16(pa, vb, o[n2], 0, 0, 0);
            }
        }

        #pragma unroll
        for (int n2 = 0; n2 < 4; ++n2) {
            const int col = h * 64 + n2 * 16 + ln;
            #pragma unroll
            for (int r = 0; r < 4; ++r) {
                const int q = q0 + quad * 4 + r;
                if (q < S_LEN)
                    out[((size_t)b * S_LEN + q) * 1024 + col] = o[n2][r];
            }
        }
    }
}

// ---------------------------------------------------------------------------
// In-place fp32 LayerNorm over last dim (1024).  grid = M_TOT rows.
// ---------------------------------------------------------------------------
__global__ __launch_bounds__(256) void ln_kernel(
    float* __restrict__ io,
    const float* __restrict__ g,
    const float* __restrict__ be)
{
    __shared__ float red[8];
    const int row = blockIdx.x;
    const int tid = threadIdx.x;
    float* p = io + (size_t)row * 1024 + tid * 4;

    const float4 u = *(const float4*)p;
    float v[4] = {u.x, u.y, u.z, u.w};
    float sum = 0.f, sq = 0.f;
    #pragma unroll
    for (int j = 0; j < 4; ++j) {
        sum += v[j];
        sq  += v[j] * v[j];
    }
    #pragma unroll
    for (int off = 1; off < 64; off <<= 1) {
        sum += __shfl_xor(sum, off);
        sq  += __shfl_xor(sq, off);
    }
    const int wv = tid >> 6, lane = tid & 63;
    if (lane == 0) { red[wv] = sum; red[4 + wv] = sq; }
    __syncthreads();
    sum = red[0] + red[1] + red[2] + red[3];
    sq  = red[4] + red[5] + red[6] + red[7];
    const float mean = sum * (1.0f / 1024.0f);
    const float var  = fmaxf(sq * (1.0f / 1024.0f) - mean * mean, 0.0f);
    const float inv  = rsqrtf(var + 1e-5f);
    const float4 gg = *(const float4*)(g + tid * 4);
    const float4 bb = *(const float4*)(be + tid * 4);
    float4 o;
    o.x = (v[0] - mean) * inv * gg.x + bb.x;
    o.y = (v[1] - mean) * inv * gg.y + bb.y;
    o.z = (v[2] - mean) * inv * gg.z + bb.z;
    o.w = (v[3] - mean) * inv * gg.w + bb.w;
    *(float4*)p = o;
}

// ---------------------------------------------------------------------------
extern "C" void kernel_launch(void* const* d_in, const int* in_sizes, int n_in,
                              void* d_out, int out_size, void* d_ws, size_t ws_size,
                              hipStream_t stream)
{
    const float* x     = (const float*)d_in[0];
    const float* Wq    = (const float*)d_in[1];
    const float* Wk    = (const float*)d_in[2];
    const float* Wv    = (const float*)d_in[3];
    const float* gamma = (const float*)d_in[4];
    const float* beta  = (const float*)d_in[5];
    float* out = (float*)d_out;

    const size_t XB  = (size_t)M_TOT * 1024 * 2;          // 46,923,776
    const size_t WBB = (size_t)3 * 1048576 * 2;           //  6,291,456
    const size_t QBB = XB, KBB = XB;
    const size_t VTB = (size_t)2048 * 64 * S_PAD * 2;     // 50,331,648
    const size_t NEED = XB + WBB + QBB + KBB + VTB;       // 197,394,432

    if (ws_size >= NEED) {
        char* ws = (char*)d_ws;
        unsigned short* xb = (unsigned short*)(ws);
        unsigned short* wb = (unsigned short*)(ws + XB);
        unsigned short* qb = (unsigned short*)(ws + XB + WBB);
        unsigned short* kb = (unsigned short*)(ws + XB + WBB + QBB);
        unsigned short* vT = (unsigned short*)(ws + XB + WBB + QBB + KBB);

        cast_all<<<25984, 256, 0, stream>>>(x, Wq, Wk, Wv, xb, wb);
        qkv_gemm2<<<dim3(179, 8, 3), 256, 0, stream>>>(xb, wb, qb, kb, vT);
        vt_pad_zero<<<8192, 256, 0, stream>>>(vT);
        attn3<<<2048, 256, 0, stream>>>(qb, kb, vT, out);
        ln_kernel<<<M_TOT, 256, 0, stream>>>(out, gamma, beta);
    } else {
        // fallback: validated zero-workspace fused path
        fused_attn<<<2048, 256, 0, stream>>>(x, Wq, Wk, Wv, out);
        ln_kernel<<<M_TOT, 256, 0, stream>>>(out, gamma, beta);
    }
}